// Round 4
// baseline (34.596 us; speedup 1.0000x reference)
//
#include <hip/hip_runtime.h>
#include <math.h>

#define NQ 5
#define D 512
#define HALF_PI 1.57079632679489662f

typedef float f32x4 __attribute__((ext_vector_type(4)));

// Analytic circuit collapse:
// z_w = -sin(HALF_PI * tanh(pre_w)) * cos(q_params[w])
// zvals = {z1 z2 z3 z4, z0 z1, z0 z1 z2, z0 z1 z2 z3, z0 z1 z2 z3 z4}
// out   = zvals @ w_post.T + b_post

// Butterfly add with DPP (pure VALU, no LDS pipe except one swizzle).
#define DPP_ADD(v, CTRL)                                                        \
    ((v) + __builtin_bit_cast(float, __builtin_amdgcn_update_dpp(               \
               0, __builtin_bit_cast(int, (v)), (CTRL), 0xF, 0xF, true)))

// Full 64-lane sum -> wave-uniform scalar.
__device__ __forceinline__ float wave_sum(float v) {
    v = DPP_ADD(v, 0xB1);   // quad_perm(1,0,3,2): xor 1
    v = DPP_ADD(v, 0x4E);   // quad_perm(2,3,0,1): xor 2
    v = DPP_ADD(v, 0x141);  // row_half_mirror  : xor 4 (quads uniform)
    v = DPP_ADD(v, 0x140);  // row_mirror       : xor 8 (8-groups uniform)
    int vi = __builtin_amdgcn_ds_swizzle(__builtin_bit_cast(int, v), 0x401F); // xor 16
    v = v + __builtin_bit_cast(float, vi);
    const int vb = __builtin_bit_cast(int, v);
    const float lo = __builtin_bit_cast(float, __builtin_amdgcn_readlane(vb, 0));
    const float hi = __builtin_bit_cast(float, __builtin_amdgcn_readlane(vb, 32));
    return lo + hi;
}

// Force a wave-uniform float into an SGPR (frees a VGPR).
__device__ __forceinline__ float uni(float v) {
    return __builtin_bit_cast(float,
        __builtin_amdgcn_readfirstlane(__builtin_bit_cast(int, v)));
}

__device__ __forceinline__ float dot8(f32x4 a, f32x4 b, f32x4 c, f32x4 d) {
    float s;
    s = a.x * b.x;
    s = fmaf(a.y, b.y, s);
    s = fmaf(a.z, b.z, s);
    s = fmaf(a.w, b.w, s);
    s = fmaf(c.x, d.x, s);
    s = fmaf(c.y, d.y, s);
    s = fmaf(c.z, d.z, s);
    s = fmaf(c.w, d.w, s);
    return s;
}

__global__ __launch_bounds__(256, 4) void dressed_qnet_kernel(
    const float* __restrict__ x,        // (B, 512)
    const float* __restrict__ w_pre,    // (5, 512)
    const float* __restrict__ b_pre,    // (5,)
    const float* __restrict__ q_params, // (5,)
    const float* __restrict__ w_post,   // (2, 5)
    const float* __restrict__ b_post,   // (2,)
    float* __restrict__ out,            // (B, 2)
    int B)
{
    const int lane = threadIdx.x & 63;
    const int wid  = (blockIdx.x * blockDim.x + threadIdx.x) >> 6;
    const int nw   = (gridDim.x * blockDim.x) >> 6;
    const int rstep = 2 * nw;           // rows per sweep

    int row0 = 2 * wid;
    if (row0 >= B) return;

    // ---- Prologue: issue first 2 rows' loads (4 KB contiguous per wave) ----
    const f32x4* p0 = reinterpret_cast<const f32x4*>(x + (size_t)row0 * D);
    f32x4 a0 = p0[lane], a1 = p0[lane + 64], b0 = p0[lane + 128], b1 = p0[lane + 192];

    // ---- Per-lane register slice of w_pre (loaded once, L1/L2-hot) ----
    f32x4 w0[NQ], w1[NQ];
#pragma unroll
    for (int q = 0; q < NQ; ++q) {
        w0[q] = *reinterpret_cast<const f32x4*>(w_pre + q * D + lane * 4);
        w1[q] = *reinterpret_cast<const f32x4*>(w_pre + q * D + 256 + lane * 4);
    }

    // ---- Wave-uniform constants -> SGPRs ----
    float bp[NQ], ct[NQ], wp0[NQ], wp1[NQ];
#pragma unroll
    for (int q = 0; q < NQ; ++q) {
        bp[q]  = uni(b_pre[q]);
        ct[q]  = uni(__cosf(q_params[q]));
        wp0[q] = uni(w_post[q]);
        wp1[q] = uni(w_post[NQ + q]);
    }
    const float bo0 = uni(b_post[0]);
    const float bo1 = uni(b_post[1]);

    // ---- Steady-state: prefetch next pair, compute current ----
    for (; row0 < B; row0 += rstep) {
        const int nrow = row0 + rstep;
        f32x4 na0, na1, nb0, nb1;
        if (nrow < B) {      // wave-uniform branch
            const f32x4* pn = reinterpret_cast<const f32x4*>(x + (size_t)nrow * D);
            na0 = pn[lane];
            na1 = pn[lane + 64];
            nb0 = pn[lane + 128];
            nb1 = pn[lane + 192];
        }

        float acc[2][NQ];
#pragma unroll
        for (int q = 0; q < NQ; ++q) {
            acc[0][q] = dot8(a0, w0[q], a1, w1[q]);
            acc[1][q] = dot8(b0, w0[q], b1, w1[q]);
        }
#pragma unroll
        for (int r = 0; r < 2; ++r)
#pragma unroll
            for (int q = 0; q < NQ; ++q)
                acc[r][q] = wave_sum(acc[r][q]);

        float o[2][2];
#pragma unroll
        for (int r = 0; r < 2; ++r) {
            float z[NQ];
#pragma unroll
            for (int q = 0; q < NQ; ++q) {
                const float pv = acc[r][q] + bp[q];
                const float e  = __expf(2.0f * pv);
                const float th = 1.0f - 2.0f / (e + 1.0f);   // tanh
                z[q] = -__sinf(HALF_PI * th) * ct[q];
            }
            const float v1   = z[0] * z[1];
            const float z234 = z[2] * z[3] * z[4];
            const float v0   = z[1] * z234;
            const float v2   = v1 * z[2];
            const float v3   = v2 * z[3];
            const float v4   = v1 * z234;

            float s0 = bo0, s1 = bo1;
            s0 = fmaf(wp0[0], v0, s0); s1 = fmaf(wp1[0], v0, s1);
            s0 = fmaf(wp0[1], v1, s0); s1 = fmaf(wp1[1], v1, s1);
            s0 = fmaf(wp0[2], v2, s0); s1 = fmaf(wp1[2], v2, s1);
            s0 = fmaf(wp0[3], v3, s0); s1 = fmaf(wp1[3], v3, s1);
            s0 = fmaf(wp0[4], v4, s0); s1 = fmaf(wp1[4], v4, s1);
            o[r][0] = s0; o[r][1] = s1;
        }

        if (lane == 0) {
            f32x4 dd = { o[0][0], o[0][1], o[1][0], o[1][1] };
            *reinterpret_cast<f32x4*>(out + (size_t)row0 * 2) = dd;
        }

        a0 = na0; a1 = na1; b0 = nb0; b1 = nb1;
    }
}

extern "C" void kernel_launch(void* const* d_in, const int* in_sizes, int n_in,
                              void* d_out, int out_size, void* d_ws, size_t ws_size,
                              hipStream_t stream) {
    const float* x        = (const float*)d_in[0];
    const float* w_pre    = (const float*)d_in[1];
    const float* b_pre    = (const float*)d_in[2];
    const float* q_params = (const float*)d_in[3];
    const float* w_post   = (const float*)d_in[4];
    const float* b_post   = (const float*)d_in[5];
    float* out = (float*)d_out;

    const int B = in_sizes[0] / D;   // 65536

    const int threads = 256;   // 4 waves/block
    const int blocks  = 2048;  // 8192 waves; 2 rows/iter -> 4 sweeps
    dressed_qnet_kernel<<<blocks, threads, 0, stream>>>(
        x, w_pre, b_pre, q_params, w_post, b_post, out, B);
}

// Round 5
// 28.324 us; speedup vs baseline: 1.2215x; 1.2215x over previous
//
#include <hip/hip_runtime.h>
#include <math.h>

#define NQ 5
#define D 512
#define HALF_PI 1.57079632679489662f

typedef float f32x4 __attribute__((ext_vector_type(4)));

// Analytic circuit collapse:
// z_w = -sin(HALF_PI * tanh(pre_w)) * cos(q_params[w])
// zvals = {z1 z2 z3 z4, z0 z1, z0 z1 z2, z0 z1 z2 z3, z0 z1 z2 z3 z4}
// out   = zvals @ w_post.T + b_post

// Butterfly add with DPP (pure VALU except one swizzle + 2 readlane).
#define DPP_ADD(v, CTRL)                                                        \
    ((v) + __builtin_bit_cast(float, __builtin_amdgcn_update_dpp(               \
               0, __builtin_bit_cast(int, (v)), (CTRL), 0xF, 0xF, true)))

__device__ __forceinline__ float wave_sum(float v) {
    v = DPP_ADD(v, 0xB1);   // quad_perm xor1
    v = DPP_ADD(v, 0x4E);   // quad_perm xor2
    v = DPP_ADD(v, 0x141);  // row_half_mirror: xor4
    v = DPP_ADD(v, 0x140);  // row_mirror: xor8
    int vi = __builtin_amdgcn_ds_swizzle(__builtin_bit_cast(int, v), 0x401F); // xor16
    v = v + __builtin_bit_cast(float, vi);
    const int vb = __builtin_bit_cast(int, v);
    const float lo = __builtin_bit_cast(float, __builtin_amdgcn_readlane(vb, 0));
    const float hi = __builtin_bit_cast(float, __builtin_amdgcn_readlane(vb, 32));
    return lo + hi;
}

__device__ __forceinline__ float uni(float v) {
    return __builtin_bit_cast(float,
        __builtin_amdgcn_readfirstlane(__builtin_bit_cast(int, v)));
}

__device__ __forceinline__ float dot8(f32x4 a, f32x4 b, f32x4 c, f32x4 d) {
    float s;
    s = a.x * b.x;
    s = fmaf(a.y, b.y, s);
    s = fmaf(a.z, b.z, s);
    s = fmaf(a.w, b.w, s);
    s = fmaf(c.x, d.x, s);
    s = fmaf(c.y, d.y, s);
    s = fmaf(c.z, d.z, s);
    s = fmaf(c.w, d.w, s);
    return s;
}

struct Uni {
    float bp[NQ], ct[NQ], wp0[NQ], wp1[NQ], bo0, bo1;
};

__device__ __forceinline__ Uni load_uniforms(const float* b_pre, const float* q_params,
                                             const float* w_post, const float* b_post) {
    Uni u;
#pragma unroll
    for (int q = 0; q < NQ; ++q) {
        u.bp[q]  = uni(b_pre[q]);
        u.ct[q]  = uni(__cosf(q_params[q]));
        u.wp0[q] = uni(w_post[q]);
        u.wp1[q] = uni(w_post[NQ + q]);
    }
    u.bo0 = uni(b_post[0]);
    u.bo1 = uni(b_post[1]);
    return u;
}

// Compute 2 rows' outputs from staged registers; store one f32x4.
__device__ __forceinline__ void compute_pair(
    const f32x4 a0, const f32x4 a1, const f32x4 b0, const f32x4 b1,
    const f32x4 w0[NQ], const f32x4 w1[NQ], const Uni& u,
    float* __restrict__ out, int row0, int lane)
{
    float acc[2][NQ];
#pragma unroll
    for (int q = 0; q < NQ; ++q) {
        acc[0][q] = dot8(a0, w0[q], a1, w1[q]);
        acc[1][q] = dot8(b0, w0[q], b1, w1[q]);
    }
#pragma unroll
    for (int r = 0; r < 2; ++r)
#pragma unroll
        for (int q = 0; q < NQ; ++q)
            acc[r][q] = wave_sum(acc[r][q]);

    float o[2][2];
#pragma unroll
    for (int r = 0; r < 2; ++r) {
        float z[NQ];
#pragma unroll
        for (int q = 0; q < NQ; ++q) {
            const float pv = acc[r][q] + u.bp[q];
            const float e  = __expf(2.0f * pv);
            const float inv = __builtin_amdgcn_rcpf(e + 1.0f);
            const float th = fmaf(-2.0f, inv, 1.0f);        // tanh(pv)
            z[q] = -__sinf(HALF_PI * th) * u.ct[q];
        }
        const float v1   = z[0] * z[1];
        const float z234 = z[2] * z[3] * z[4];
        const float v0   = z[1] * z234;
        const float v2   = v1 * z[2];
        const float v3   = v2 * z[3];
        const float v4   = v1 * z234;

        float s0 = u.bo0, s1 = u.bo1;
        s0 = fmaf(u.wp0[0], v0, s0); s1 = fmaf(u.wp1[0], v0, s1);
        s0 = fmaf(u.wp0[1], v1, s0); s1 = fmaf(u.wp1[1], v1, s1);
        s0 = fmaf(u.wp0[2], v2, s0); s1 = fmaf(u.wp1[2], v2, s1);
        s0 = fmaf(u.wp0[3], v3, s0); s1 = fmaf(u.wp1[3], v3, s1);
        s0 = fmaf(u.wp0[4], v4, s0); s1 = fmaf(u.wp1[4], v4, s1);
        o[r][0] = s0; o[r][1] = s1;
    }

    if (lane == 0) {
        f32x4 dd = { o[0][0], o[0][1], o[1][0], o[1][1] };
        *reinterpret_cast<f32x4*>(out + (size_t)row0 * 2) = dd;
    }
}

// ---------------- Fast path: B == 2 * n_waves * ITERS, branchless ----------------
// Fully unrolled, 2-deep unconditional prefetch -> compiler emits counted vmcnt;
// 8 KB per wave stays in flight across each compute phase.
template<int ITERS>
__global__ __launch_bounds__(256, 4) void dressed_qnet_fast(
    const float* __restrict__ x, const float* __restrict__ w_pre,
    const float* __restrict__ b_pre, const float* __restrict__ q_params,
    const float* __restrict__ w_post, const float* __restrict__ b_post,
    float* __restrict__ out)
{
    const int lane = threadIdx.x & 63;
    const int wid  = (blockIdx.x * blockDim.x + threadIdx.x) >> 6;
    const int nw   = (gridDim.x * blockDim.x) >> 6;
    const int rstep = 2 * nw;

    const f32x4* xb = reinterpret_cast<const f32x4*>(x);   // 128 f32x4 per row

    f32x4 A0[ITERS], A1[ITERS], B0[ITERS], B1[ITERS];

#define ISSUE(j)                                                                \
    do {                                                                        \
        const f32x4* p = xb + (size_t)(2 * wid + (j) * rstep) * 128;            \
        A0[j] = p[lane];                                                        \
        A1[j] = p[lane + 64];                                                   \
        B0[j] = p[lane + 128];                                                  \
        B1[j] = p[lane + 192];                                                  \
    } while (0)

    ISSUE(0);
    if (ITERS > 1) ISSUE(1);

    f32x4 w0[NQ], w1[NQ];
#pragma unroll
    for (int q = 0; q < NQ; ++q) {
        w0[q] = *reinterpret_cast<const f32x4*>(w_pre + q * D + lane * 4);
        w1[q] = *reinterpret_cast<const f32x4*>(w_pre + q * D + 256 + lane * 4);
    }
    const Uni u = load_uniforms(b_pre, q_params, w_post, b_post);

#pragma unroll
    for (int j = 0; j < ITERS; ++j) {
        if (j + 2 < ITERS) ISSUE(j + 2);          // compile-time condition
        compute_pair(A0[j], A1[j], B0[j], B1[j], w0, w1, u,
                     out, 2 * wid + j * rstep, lane);
    }
#undef ISSUE
}

// ---------------- Generic fallback (any B) ----------------
__global__ __launch_bounds__(256, 4) void dressed_qnet_generic(
    const float* __restrict__ x, const float* __restrict__ w_pre,
    const float* __restrict__ b_pre, const float* __restrict__ q_params,
    const float* __restrict__ w_post, const float* __restrict__ b_post,
    float* __restrict__ out, int B)
{
    const int lane = threadIdx.x & 63;
    const int wid  = (blockIdx.x * blockDim.x + threadIdx.x) >> 6;
    const int nw   = (gridDim.x * blockDim.x) >> 6;
    const int rstep = 2 * nw;

    f32x4 w0[NQ], w1[NQ];
#pragma unroll
    for (int q = 0; q < NQ; ++q) {
        w0[q] = *reinterpret_cast<const f32x4*>(w_pre + q * D + lane * 4);
        w1[q] = *reinterpret_cast<const f32x4*>(w_pre + q * D + 256 + lane * 4);
    }
    const Uni u = load_uniforms(b_pre, q_params, w_post, b_post);

    for (int row0 = 2 * wid; row0 < B; row0 += rstep) {
        const f32x4* p = reinterpret_cast<const f32x4*>(x + (size_t)row0 * D);
        const f32x4 a0 = p[lane], a1 = p[lane + 64];
        f32x4 b0, b1;
        const bool have2 = (row0 + 1 < B);
        const int roff = have2 ? 128 : 0;
        b0 = p[lane + roff];
        b1 = p[lane + 64 + roff];

        if (have2) {
            compute_pair(a0, a1, b0, b1, w0, w1, u, out, row0, lane);
        } else {
            float acc[NQ];
#pragma unroll
            for (int q = 0; q < NQ; ++q) acc[q] = wave_sum(dot8(a0, w0[q], a1, w1[q]));
            float z[NQ];
#pragma unroll
            for (int q = 0; q < NQ; ++q) {
                const float pv = acc[q] + u.bp[q];
                const float e  = __expf(2.0f * pv);
                const float inv = __builtin_amdgcn_rcpf(e + 1.0f);
                const float th = fmaf(-2.0f, inv, 1.0f);
                z[q] = -__sinf(HALF_PI * th) * u.ct[q];
            }
            const float v1 = z[0] * z[1];
            const float z234 = z[2] * z[3] * z[4];
            const float v0 = z[1] * z234, v2 = v1 * z[2];
            const float v3 = v2 * z[3],  v4 = v1 * z234;
            float s0 = u.bo0, s1 = u.bo1;
            s0 = fmaf(u.wp0[0], v0, s0); s1 = fmaf(u.wp1[0], v0, s1);
            s0 = fmaf(u.wp0[1], v1, s0); s1 = fmaf(u.wp1[1], v1, s1);
            s0 = fmaf(u.wp0[2], v2, s0); s1 = fmaf(u.wp1[2], v2, s1);
            s0 = fmaf(u.wp0[3], v3, s0); s1 = fmaf(u.wp1[3], v3, s1);
            s0 = fmaf(u.wp0[4], v4, s0); s1 = fmaf(u.wp1[4], v4, s1);
            if (lane == 0) {
                out[(size_t)row0 * 2 + 0] = s0;
                out[(size_t)row0 * 2 + 1] = s1;
            }
        }
    }
}

extern "C" void kernel_launch(void* const* d_in, const int* in_sizes, int n_in,
                              void* d_out, int out_size, void* d_ws, size_t ws_size,
                              hipStream_t stream) {
    const float* x        = (const float*)d_in[0];
    const float* w_pre    = (const float*)d_in[1];
    const float* b_pre    = (const float*)d_in[2];
    const float* q_params = (const float*)d_in[3];
    const float* w_post   = (const float*)d_in[4];
    const float* b_post   = (const float*)d_in[5];
    float* out = (float*)d_out;

    const int B = in_sizes[0] / D;   // 65536

    const int threads = 256;         // 4 waves/block
    const int blocks  = 2048;        // 8192 waves
    const int nw = blocks * (threads / 64);
    const int rows_per_sweep = 2 * nw;

    if (B == rows_per_sweep * 4) {
        dressed_qnet_fast<4><<<blocks, threads, 0, stream>>>(
            x, w_pre, b_pre, q_params, w_post, b_post, out);
    } else if (B == rows_per_sweep * 2) {
        dressed_qnet_fast<2><<<blocks, threads, 0, stream>>>(
            x, w_pre, b_pre, q_params, w_post, b_post, out);
    } else if (B == rows_per_sweep) {
        dressed_qnet_fast<1><<<blocks, threads, 0, stream>>>(
            x, w_pre, b_pre, q_params, w_post, b_post, out);
    } else {
        dressed_qnet_generic<<<blocks, threads, 0, stream>>>(
            x, w_pre, b_pre, q_params, w_post, b_post, out, B);
    }
}

// Round 6
// 28.180 us; speedup vs baseline: 1.2277x; 1.0051x over previous
//
#include <hip/hip_runtime.h>
#include <math.h>

#define NQ 5
#define D 512
#define HALF_PI 1.57079632679489662f

typedef float f32x4 __attribute__((ext_vector_type(4)));

// Analytic circuit collapse:
// z_w = -sin(HALF_PI * tanh(pre_w)) * cos(q_params[w])
// zvals = {z1 z2 z3 z4, z0 z1, z0 z1 z2, z0 z1 z2 z3, z0 z1 z2 z3 z4}
// out   = zvals @ w_post.T + b_post

#define DPP_ADD(v, CTRL)                                                        \
    ((v) + __builtin_bit_cast(float, __builtin_amdgcn_update_dpp(               \
               0, __builtin_bit_cast(int, (v)), (CTRL), 0xF, 0xF, true)))

__device__ __forceinline__ float wave_sum(float v) {
    v = DPP_ADD(v, 0xB1);   // quad_perm xor1
    v = DPP_ADD(v, 0x4E);   // quad_perm xor2
    v = DPP_ADD(v, 0x141);  // row_half_mirror: xor4
    v = DPP_ADD(v, 0x140);  // row_mirror: xor8
    int vi = __builtin_amdgcn_ds_swizzle(__builtin_bit_cast(int, v), 0x401F); // xor16
    v = v + __builtin_bit_cast(float, vi);
    const int vb = __builtin_bit_cast(int, v);
    const float lo = __builtin_bit_cast(float, __builtin_amdgcn_readlane(vb, 0));
    const float hi = __builtin_bit_cast(float, __builtin_amdgcn_readlane(vb, 32));
    return lo + hi;
}

__device__ __forceinline__ float uni(float v) {
    return __builtin_bit_cast(float,
        __builtin_amdgcn_readfirstlane(__builtin_bit_cast(int, v)));
}

__device__ __forceinline__ float dot8(f32x4 a, f32x4 b, f32x4 c, f32x4 d) {
    float s;
    s = a.x * b.x;
    s = fmaf(a.y, b.y, s);
    s = fmaf(a.z, b.z, s);
    s = fmaf(a.w, b.w, s);
    s = fmaf(c.x, d.x, s);
    s = fmaf(c.y, d.y, s);
    s = fmaf(c.z, d.z, s);
    s = fmaf(c.w, d.w, s);
    return s;
}

struct Uni {
    float bp[NQ], ct[NQ], wp0[NQ], wp1[NQ], bo0, bo1;
};

__device__ __forceinline__ Uni load_uniforms(const float* b_pre, const float* q_params,
                                             const float* w_post, const float* b_post) {
    Uni u;
#pragma unroll
    for (int q = 0; q < NQ; ++q) {
        u.bp[q]  = uni(b_pre[q]);
        u.ct[q]  = uni(__cosf(q_params[q]));
        u.wp0[q] = uni(w_post[q]);
        u.wp1[q] = uni(w_post[NQ + q]);
    }
    u.bo0 = uni(b_post[0]);
    u.bo1 = uni(b_post[1]);
    return u;
}

// Compute 2 rows' outputs from staged registers; store one f32x4.
__device__ __forceinline__ void compute_pair(
    const f32x4 a0, const f32x4 a1, const f32x4 b0, const f32x4 b1,
    const f32x4 w0[NQ], const f32x4 w1[NQ], const Uni& u,
    float* __restrict__ out, int row0, int lane)
{
    float acc[2][NQ];
#pragma unroll
    for (int q = 0; q < NQ; ++q) {
        acc[0][q] = dot8(a0, w0[q], a1, w1[q]);
        acc[1][q] = dot8(b0, w0[q], b1, w1[q]);
    }
#pragma unroll
    for (int r = 0; r < 2; ++r)
#pragma unroll
        for (int q = 0; q < NQ; ++q)
            acc[r][q] = wave_sum(acc[r][q]);

    float o[2][2];
#pragma unroll
    for (int r = 0; r < 2; ++r) {
        float z[NQ];
#pragma unroll
        for (int q = 0; q < NQ; ++q) {
            const float pv = acc[r][q] + u.bp[q];
            const float e  = __expf(2.0f * pv);
            const float inv = __builtin_amdgcn_rcpf(e + 1.0f);
            const float th = fmaf(-2.0f, inv, 1.0f);        // tanh(pv)
            z[q] = -__sinf(HALF_PI * th) * u.ct[q];
        }
        const float v1   = z[0] * z[1];
        const float z234 = z[2] * z[3] * z[4];
        const float v0   = z[1] * z234;
        const float v2   = v1 * z[2];
        const float v3   = v2 * z[3];
        const float v4   = v1 * z234;

        float s0 = u.bo0, s1 = u.bo1;
        s0 = fmaf(u.wp0[0], v0, s0); s1 = fmaf(u.wp1[0], v0, s1);
        s0 = fmaf(u.wp0[1], v1, s0); s1 = fmaf(u.wp1[1], v1, s1);
        s0 = fmaf(u.wp0[2], v2, s0); s1 = fmaf(u.wp1[2], v2, s1);
        s0 = fmaf(u.wp0[3], v3, s0); s1 = fmaf(u.wp1[3], v3, s1);
        s0 = fmaf(u.wp0[4], v4, s0); s1 = fmaf(u.wp1[4], v4, s1);
        o[r][0] = s0; o[r][1] = s1;
    }

    if (lane == 0) {
        f32x4 dd = { o[0][0], o[0][1], o[1][0], o[1][1] };
        *reinterpret_cast<f32x4*>(out + (size_t)row0 * 2) = dd;
    }
}

// ---------------- Fast path: persistent grid, B == 2 * n_waves * ITERS ----------------
// Exactly-resident grid (2 blocks/CU at <=128 VGPR): ONE pipeline prologue and ONE
// drain for the whole kernel. 3-slot rotating staging buffer, prefetch distance 2
// (8 KB/wave in flight), all indices compile-time after full unroll.
template<int ITERS>
__global__ __launch_bounds__(256, 4) void dressed_qnet_fast(
    const float* __restrict__ x, const float* __restrict__ w_pre,
    const float* __restrict__ b_pre, const float* __restrict__ q_params,
    const float* __restrict__ w_post, const float* __restrict__ b_post,
    float* __restrict__ out)
{
    const int lane = threadIdx.x & 63;
    const int wid  = (blockIdx.x * blockDim.x + threadIdx.x) >> 6;
    const int nw   = (gridDim.x * blockDim.x) >> 6;
    const int rstep = 2 * nw;

    const f32x4* xb = reinterpret_cast<const f32x4*>(x);   // 128 f32x4 per row

    f32x4 S[3][4];   // rotating staging: slot j%3 holds iteration j's 2 rows

#define ISSUE(slot, j)                                                          \
    do {                                                                        \
        const f32x4* p = xb + (size_t)(2 * wid + (j) * rstep) * 128;            \
        S[slot][0] = __builtin_nontemporal_load(p + lane);                      \
        S[slot][1] = __builtin_nontemporal_load(p + lane + 64);                 \
        S[slot][2] = __builtin_nontemporal_load(p + lane + 128);                \
        S[slot][3] = __builtin_nontemporal_load(p + lane + 192);                \
    } while (0)

    ISSUE(0, 0);
    if (ITERS > 1) ISSUE(1, 1);

    f32x4 w0[NQ], w1[NQ];
#pragma unroll
    for (int q = 0; q < NQ; ++q) {
        w0[q] = *reinterpret_cast<const f32x4*>(w_pre + q * D + lane * 4);
        w1[q] = *reinterpret_cast<const f32x4*>(w_pre + q * D + 256 + lane * 4);
    }
    const Uni u = load_uniforms(b_pre, q_params, w_post, b_post);

#pragma unroll
    for (int j = 0; j < ITERS; ++j) {
        const int cs = j % 3;
        const int ns = (j + 2) % 3;
        if (j + 2 < ITERS) ISSUE(ns, j + 2);      // compile-time condition & slots
        compute_pair(S[cs][0], S[cs][1], S[cs][2], S[cs][3], w0, w1, u,
                     out, 2 * wid + j * rstep, lane);
    }
#undef ISSUE
}

// ---------------- Generic fallback (any B) ----------------
__global__ __launch_bounds__(256, 4) void dressed_qnet_generic(
    const float* __restrict__ x, const float* __restrict__ w_pre,
    const float* __restrict__ b_pre, const float* __restrict__ q_params,
    const float* __restrict__ w_post, const float* __restrict__ b_post,
    float* __restrict__ out, int B)
{
    const int lane = threadIdx.x & 63;
    const int wid  = (blockIdx.x * blockDim.x + threadIdx.x) >> 6;
    const int nw   = (gridDim.x * blockDim.x) >> 6;
    const int rstep = 2 * nw;

    f32x4 w0[NQ], w1[NQ];
#pragma unroll
    for (int q = 0; q < NQ; ++q) {
        w0[q] = *reinterpret_cast<const f32x4*>(w_pre + q * D + lane * 4);
        w1[q] = *reinterpret_cast<const f32x4*>(w_pre + q * D + 256 + lane * 4);
    }
    const Uni u = load_uniforms(b_pre, q_params, w_post, b_post);

    for (int row0 = 2 * wid; row0 < B; row0 += rstep) {
        const f32x4* p = reinterpret_cast<const f32x4*>(x + (size_t)row0 * D);
        const f32x4 a0 = p[lane], a1 = p[lane + 64];
        f32x4 b0, b1;
        const bool have2 = (row0 + 1 < B);
        const int roff = have2 ? 128 : 0;
        b0 = p[lane + roff];
        b1 = p[lane + 64 + roff];

        if (have2) {
            compute_pair(a0, a1, b0, b1, w0, w1, u, out, row0, lane);
        } else {
            float acc[NQ];
#pragma unroll
            for (int q = 0; q < NQ; ++q) acc[q] = wave_sum(dot8(a0, w0[q], a1, w1[q]));
            float z[NQ];
#pragma unroll
            for (int q = 0; q < NQ; ++q) {
                const float pv = acc[q] + u.bp[q];
                const float e  = __expf(2.0f * pv);
                const float inv = __builtin_amdgcn_rcpf(e + 1.0f);
                const float th = fmaf(-2.0f, inv, 1.0f);
                z[q] = -__sinf(HALF_PI * th) * u.ct[q];
            }
            const float v1 = z[0] * z[1];
            const float z234 = z[2] * z[3] * z[4];
            const float v0 = z[1] * z234, v2 = v1 * z[2];
            const float v3 = v2 * z[3],  v4 = v1 * z234;
            float s0 = u.bo0, s1 = u.bo1;
            s0 = fmaf(u.wp0[0], v0, s0); s1 = fmaf(u.wp1[0], v0, s1);
            s0 = fmaf(u.wp0[1], v1, s0); s1 = fmaf(u.wp1[1], v1, s1);
            s0 = fmaf(u.wp0[2], v2, s0); s1 = fmaf(u.wp1[2], v2, s1);
            s0 = fmaf(u.wp0[3], v3, s0); s1 = fmaf(u.wp1[3], v3, s1);
            s0 = fmaf(u.wp0[4], v4, s0); s1 = fmaf(u.wp1[4], v4, s1);
            if (lane == 0) {
                out[(size_t)row0 * 2 + 0] = s0;
                out[(size_t)row0 * 2 + 1] = s1;
            }
        }
    }
}

extern "C" void kernel_launch(void* const* d_in, const int* in_sizes, int n_in,
                              void* d_out, int out_size, void* d_ws, size_t ws_size,
                              hipStream_t stream) {
    const float* x        = (const float*)d_in[0];
    const float* w_pre    = (const float*)d_in[1];
    const float* b_pre    = (const float*)d_in[2];
    const float* q_params = (const float*)d_in[3];
    const float* w_post   = (const float*)d_in[4];
    const float* b_post   = (const float*)d_in[5];
    float* out = (float*)d_out;

    const int B = in_sizes[0] / D;   // 65536

    // Persistent grid: 512 blocks x 4 waves = 2048 waves, exactly resident
    // (2 blocks/CU at <=128 VGPR on 256 CUs).
    const int threads = 256;
    const int blocks  = 512;
    const int nw = blocks * (threads / 64);          // 2048 waves
    const int rows_per_sweep = 2 * nw;               // 4096 rows

    if (B == rows_per_sweep * 16) {
        dressed_qnet_fast<16><<<blocks, threads, 0, stream>>>(
            x, w_pre, b_pre, q_params, w_post, b_post, out);
    } else if (B == rows_per_sweep * 8) {
        dressed_qnet_fast<8><<<blocks, threads, 0, stream>>>(
            x, w_pre, b_pre, q_params, w_post, b_post, out);
    } else if (B == rows_per_sweep * 4) {
        dressed_qnet_fast<4><<<blocks, threads, 0, stream>>>(
            x, w_pre, b_pre, q_params, w_post, b_post, out);
    } else if (B == rows_per_sweep * 2) {
        dressed_qnet_fast<2><<<blocks, threads, 0, stream>>>(
            x, w_pre, b_pre, q_params, w_post, b_post, out);
    } else if (B == rows_per_sweep) {
        dressed_qnet_fast<1><<<blocks, threads, 0, stream>>>(
            x, w_pre, b_pre, q_params, w_post, b_post, out);
    } else {
        // generic path: bigger grid for load balance on odd shapes
        dressed_qnet_generic<<<2048, threads, 0, stream>>>(
            x, w_pre, b_pre, q_params, w_post, b_post, out, B);
    }
}

// Round 7
// 27.429 us; speedup vs baseline: 1.2613x; 1.0274x over previous
//
#include <hip/hip_runtime.h>
#include <math.h>

#define NQ 5
#define D 512
#define HALF_PI 1.57079632679489662f

typedef float f32x4 __attribute__((ext_vector_type(4)));

// Analytic circuit collapse:
// z_w = -sin(HALF_PI * tanh(pre_w)) * cos(q_params[w])
// zvals = {z1 z2 z3 z4, z0 z1, z0 z1 z2, z0 z1 z2 z3, z0 z1 z2 z3 z4}
// out   = zvals @ w_post.T + b_post

#define DPP_ADD(v, CTRL)                                                        \
    ((v) + __builtin_bit_cast(float, __builtin_amdgcn_update_dpp(               \
               0, __builtin_bit_cast(int, (v)), (CTRL), 0xF, 0xF, true)))

__device__ __forceinline__ float wave_sum(float v) {
    v = DPP_ADD(v, 0xB1);   // quad_perm xor1
    v = DPP_ADD(v, 0x4E);   // quad_perm xor2
    v = DPP_ADD(v, 0x141);  // row_half_mirror: xor4
    v = DPP_ADD(v, 0x140);  // row_mirror: xor8
    int vi = __builtin_amdgcn_ds_swizzle(__builtin_bit_cast(int, v), 0x401F); // xor16
    v = v + __builtin_bit_cast(float, vi);
    const int vb = __builtin_bit_cast(int, v);
    const float lo = __builtin_bit_cast(float, __builtin_amdgcn_readlane(vb, 0));
    const float hi = __builtin_bit_cast(float, __builtin_amdgcn_readlane(vb, 32));
    return lo + hi;
}

__device__ __forceinline__ float uni(float v) {
    return __builtin_bit_cast(float,
        __builtin_amdgcn_readfirstlane(__builtin_bit_cast(int, v)));
}

__device__ __forceinline__ float dot8(f32x4 a, f32x4 b, f32x4 c, f32x4 d) {
    float s;
    s = a.x * b.x;
    s = fmaf(a.y, b.y, s);
    s = fmaf(a.z, b.z, s);
    s = fmaf(a.w, b.w, s);
    s = fmaf(c.x, d.x, s);
    s = fmaf(c.y, d.y, s);
    s = fmaf(c.z, d.z, s);
    s = fmaf(c.w, d.w, s);
    return s;
}

struct Uni {
    float bp[NQ], ct[NQ], wp0[NQ], wp1[NQ], bo0, bo1;
};

__device__ __forceinline__ Uni load_uniforms(const float* b_pre, const float* q_params,
                                             const float* w_post, const float* b_post) {
    Uni u;
#pragma unroll
    for (int q = 0; q < NQ; ++q) {
        u.bp[q]  = uni(b_pre[q]);
        u.ct[q]  = uni(__cosf(q_params[q]));
        u.wp0[q] = uni(w_post[q]);
        u.wp1[q] = uni(w_post[NQ + q]);
    }
    u.bo0 = uni(b_post[0]);
    u.bo1 = uni(b_post[1]);
    return u;
}

// Per-lane epilogue: 5 pre-activations -> 2 outputs (each lane owns one row).
__device__ __forceinline__ void epilogue(const float dep[NQ], const Uni& u,
                                         float& o0, float& o1) {
    float z[NQ];
#pragma unroll
    for (int q = 0; q < NQ; ++q) {
        const float pv = dep[q] + u.bp[q];
        const float e  = __expf(2.0f * pv);
        const float inv = __builtin_amdgcn_rcpf(e + 1.0f);
        const float th = fmaf(-2.0f, inv, 1.0f);        // tanh(pv)
        z[q] = -__sinf(HALF_PI * th) * u.ct[q];
    }
    const float v1   = z[0] * z[1];
    const float z234 = z[2] * z[3] * z[4];
    const float v0   = z[1] * z234;
    const float v2   = v1 * z[2];
    const float v3   = v2 * z[3];
    const float v4   = v1 * z234;

    o0 = u.bo0; o1 = u.bo1;
    o0 = fmaf(u.wp0[0], v0, o0); o1 = fmaf(u.wp1[0], v0, o1);
    o0 = fmaf(u.wp0[1], v1, o0); o1 = fmaf(u.wp1[1], v1, o1);
    o0 = fmaf(u.wp0[2], v2, o0); o1 = fmaf(u.wp1[2], v2, o1);
    o0 = fmaf(u.wp0[3], v3, o0); o1 = fmaf(u.wp1[3], v3, o1);
    o0 = fmaf(u.wp0[4], v4, o0); o1 = fmaf(u.wp1[4], v4, o1);
}

// ---------------- Fast path: B == 2 * n_waves * ITERS (ITERS <= 32) ----------------
// Per-iteration work is ONLY {issue 4 loads, 10 dot8, 10 wave_sum, 12-instr deposit}.
// The transcendental epilogue for all ITERS*2 rows runs ONCE at the end, lane-parallel
// (lane k owns row pair-index k). ~30% VALU cut per iteration -> tighter mem overlap.
template<int ITERS>
__global__ __launch_bounds__(256, 4) void dressed_qnet_fast(
    const float* __restrict__ x, const float* __restrict__ w_pre,
    const float* __restrict__ b_pre, const float* __restrict__ q_params,
    const float* __restrict__ w_post, const float* __restrict__ b_post,
    float* __restrict__ out)
{
    const int lane = threadIdx.x & 63;
    const int wid  = (blockIdx.x * blockDim.x + threadIdx.x) >> 6;
    const int nw   = (gridDim.x * blockDim.x) >> 6;
    const int rstep = 2 * nw;

    const f32x4* xb = reinterpret_cast<const f32x4*>(x);   // 128 f32x4 per row

    f32x4 S[3][4];   // rotating staging: slot j%3 holds iteration j's 2 rows

#define ISSUE(slot, j)                                                          \
    do {                                                                        \
        const f32x4* p = xb + (size_t)(2 * wid + (j) * rstep) * 128;            \
        S[slot][0] = p[lane];                                                   \
        S[slot][1] = p[lane + 64];                                              \
        S[slot][2] = p[lane + 128];                                             \
        S[slot][3] = p[lane + 192];                                             \
    } while (0)

    ISSUE(0, 0);
    if (ITERS > 1) ISSUE(1, 1);

    f32x4 w0[NQ], w1[NQ];
#pragma unroll
    for (int q = 0; q < NQ; ++q) {
        w0[q] = *reinterpret_cast<const f32x4*>(w_pre + q * D + lane * 4);
        w1[q] = *reinterpret_cast<const f32x4*>(w_pre + q * D + 256 + lane * 4);
    }
    const Uni u = load_uniforms(b_pre, q_params, w_post, b_post);

    float dep[NQ];   // lane (2j+r) accumulates iteration j, row r's 5 dots
#pragma unroll
    for (int q = 0; q < NQ; ++q) dep[q] = 0.0f;

#pragma unroll
    for (int j = 0; j < ITERS; ++j) {
        const int cs = j % 3;
        const int ns = (j + 2) % 3;
        if (j + 2 < ITERS) ISSUE(ns, j + 2);      // compile-time condition & slots

        float acc[2][NQ];
#pragma unroll
        for (int q = 0; q < NQ; ++q) {
            acc[0][q] = dot8(S[cs][0], w0[q], S[cs][1], w1[q]);
            acc[1][q] = dot8(S[cs][2], w0[q], S[cs][3], w1[q]);
        }
        const bool is0 = (lane == 2 * j);
        const bool is1 = (lane == 2 * j + 1);
#pragma unroll
        for (int q = 0; q < NQ; ++q) {
            const float r0 = wave_sum(acc[0][q]);
            const float r1 = wave_sum(acc[1][q]);
            dep[q] = is0 ? r0 : dep[q];
            dep[q] = is1 ? r1 : dep[q];
        }
    }
#undef ISSUE

    // ---- One lane-parallel epilogue for all 2*ITERS rows ----
    float o0, o1;
    epilogue(dep, u, o0, o1);

    if (lane < 2 * ITERS) {
        const int row = 2 * wid + (lane >> 1) * rstep + (lane & 1);
        *reinterpret_cast<float2*>(out + (size_t)row * 2) = make_float2(o0, o1);
    }
}

// ---------------- Generic fallback (any B) ----------------
__global__ __launch_bounds__(256, 4) void dressed_qnet_generic(
    const float* __restrict__ x, const float* __restrict__ w_pre,
    const float* __restrict__ b_pre, const float* __restrict__ q_params,
    const float* __restrict__ w_post, const float* __restrict__ b_post,
    float* __restrict__ out, int B)
{
    const int lane = threadIdx.x & 63;
    const int wid  = (blockIdx.x * blockDim.x + threadIdx.x) >> 6;
    const int nw   = (gridDim.x * blockDim.x) >> 6;

    f32x4 w0[NQ], w1[NQ];
#pragma unroll
    for (int q = 0; q < NQ; ++q) {
        w0[q] = *reinterpret_cast<const f32x4*>(w_pre + q * D + lane * 4);
        w1[q] = *reinterpret_cast<const f32x4*>(w_pre + q * D + 256 + lane * 4);
    }
    const Uni u = load_uniforms(b_pre, q_params, w_post, b_post);

    for (int row = wid; row < B; row += nw) {
        const f32x4* p = reinterpret_cast<const f32x4*>(x + (size_t)row * D);
        const f32x4 a0 = p[lane], a1 = p[lane + 64];
        float dep[NQ];
#pragma unroll
        for (int q = 0; q < NQ; ++q)
            dep[q] = wave_sum(dot8(a0, w0[q], a1, w1[q]));
        float o0, o1;
        epilogue(dep, u, o0, o1);
        if (lane == 0)
            *reinterpret_cast<float2*>(out + (size_t)row * 2) = make_float2(o0, o1);
    }
}

extern "C" void kernel_launch(void* const* d_in, const int* in_sizes, int n_in,
                              void* d_out, int out_size, void* d_ws, size_t ws_size,
                              hipStream_t stream) {
    const float* x        = (const float*)d_in[0];
    const float* w_pre    = (const float*)d_in[1];
    const float* b_pre    = (const float*)d_in[2];
    const float* q_params = (const float*)d_in[3];
    const float* w_post   = (const float*)d_in[4];
    const float* b_post   = (const float*)d_in[5];
    float* out = (float*)d_out;

    const int B = in_sizes[0] / D;   // 65536

    const int threads = 256;          // 4 waves/block
    const int blocks  = 1024;         // 4096 waves -> 4 waves/SIMD potential
    const int nw = blocks * (threads / 64);          // 4096
    const int rows_per_sweep = 2 * nw;               // 8192

    if (B == rows_per_sweep * 8) {
        dressed_qnet_fast<8><<<blocks, threads, 0, stream>>>(
            x, w_pre, b_pre, q_params, w_post, b_post, out);
    } else if (B == rows_per_sweep * 4) {
        dressed_qnet_fast<4><<<blocks, threads, 0, stream>>>(
            x, w_pre, b_pre, q_params, w_post, b_post, out);
    } else if (B == rows_per_sweep * 2) {
        dressed_qnet_fast<2><<<blocks, threads, 0, stream>>>(
            x, w_pre, b_pre, q_params, w_post, b_post, out);
    } else if (B == rows_per_sweep) {
        dressed_qnet_fast<1><<<blocks, threads, 0, stream>>>(
            x, w_pre, b_pre, q_params, w_post, b_post, out);
    } else {
        dressed_qnet_generic<<<2048, threads, 0, stream>>>(
            x, w_pre, b_pre, q_params, w_post, b_post, out, B);
    }
}